// Round 12
// baseline (168.508 us; speedup 1.0000x reference)
//
#include <hip/hip_runtime.h>
#include <hip/hip_bf16.h>

// Problem constants
#define B_SZ 256
#define SDIM 1024
#define ADIM 512

#define NCHUNK 16            // chunks per block (K-half / 32)
#define RING 5               // LDS ring depth (chunks)

typedef __attribute__((ext_vector_type(8))) short bf16x8;
typedef __attribute__((ext_vector_type(4))) float f32x4;

__device__ __forceinline__ unsigned short f2bf(float x) {
  union { float f; unsigned u; } v; v.f = x;
  unsigned r = v.u + 0x7FFFu + ((v.u >> 16) & 1u);   // round-to-nearest-even
  return (unsigned short)(r >> 16);
}

__device__ __forceinline__ void gll16(const void* g, void* l) {
  __builtin_amdgcn_global_load_lds(
      (const __attribute__((address_space(1))) unsigned int*)g,
      (__attribute__((address_space(3))) unsigned int*)l, 16, 0, 0);
}

__device__ __forceinline__ unsigned cvtpk(float lo, float hi) {
  unsigned r;
  asm("v_cvt_pk_bf16_f32 %0, %1, %2" : "=v"(r) : "v"(lo), "v"(hi));
  return r;
}

// ---------------- Kernel 1: small MLPs + obsT fragment layout + cw2b dot --------
// obsT layout: [32 kc][4 g][256 b][8] bf16  (k = kc*32 + g*8 + j)
__global__ __launch_bounds__(128) void kprep(
    const float* __restrict__ obs,
    const float* __restrict__ task, const int* __restrict__ action,
    const float* __restrict__ we1, const float* __restrict__ be1,
    const float* __restrict__ we2, const float* __restrict__ be2,
    const float* __restrict__ aw1, const float* __restrict__ aw1b,
    const float* __restrict__ ab1, const float* __restrict__ ab1b,
    const float* __restrict__ ab2, const float* __restrict__ ab2b,
    const float* __restrict__ cw1, const float* __restrict__ cw1b,
    const float* __restrict__ cb1, const float* __restrict__ cb1b,
    const float* __restrict__ cb2, const float* __restrict__ cb2b,
    const float* __restrict__ cw2b,
    float* __restrict__ ws_ha, float* __restrict__ ws_hc,
    unsigned short* __restrict__ obsT,
    float* __restrict__ out)
{
  const int b = blockIdx.x, t = threadIdx.x;
  __shared__ float s_task[64], s_t1[64], s_z[64], s_hb[128], s_red[128];

  float dotc = 0.0f;
  {
    const int kc = t >> 2, g = t & 3;
    const float4* src = (const float4*)(obs + (size_t)b * SDIM + kc * 32 + g * 8);
    const float4* cbp = (const float4*)(cw2b + kc * 32 + g * 8);
    float4 x = src[0], y = src[1];
    float4 c0 = cbp[0], c1 = cbp[1];
    dotc = x.x * c0.x + x.y * c0.y + x.z * c0.z + x.w * c0.w
         + y.x * c1.x + y.y * c1.y + y.z * c1.z + y.w * c1.w;
    ushort4 u0, u1;
    u0.x = f2bf(x.x); u0.y = f2bf(x.y); u0.z = f2bf(x.z); u0.w = f2bf(x.w);
    u1.x = f2bf(y.x); u1.y = f2bf(y.y); u1.z = f2bf(y.z); u1.w = f2bf(y.w);
    ushort4* d = (ushort4*)(obsT + ((size_t)(kc * 4 + g) * 256 + b) * 8);
    d[0] = u0; d[1] = u1;
  }

  if (t < 64) s_task[t] = task[b * 64 + t];
  __syncthreads();
  if (t < 64) {
    float a = be1[t];
    for (int e = 0; e < 64; ++e) a += s_task[e] * we1[e * 64 + t];
    s_t1[t] = fmaxf(a, 0.0f);
  }
  __syncthreads();
  if (t < 64) {
    float a = be2[t];
    for (int e = 0; e < 64; ++e) a += s_t1[e] * we2[e * 64 + t];
    s_z[t] = fmaxf(a, 0.0f);
  }
  __syncthreads();
  {
    float a1 = aw1b[t], a2 = ab1b[t], a3 = cw1b[t], a4 = cb1b[t];
    for (int e = 0; e < 64; ++e) {
      const float zv = s_z[e];
      a1 += zv * aw1[e * 128 + t];
      a2 += zv * ab1[e * 128 + t];
      a3 += zv * cw1[e * 128 + t];
      a4 += zv * cb1[e * 128 + t];
    }
    ws_ha[b * 128 + t] = fmaxf(a1, 0.0f);
    s_hb[t] = fmaxf(a2, 0.0f);
    ws_hc[b * 128 + t] = fmaxf(a3, 0.0f);
    s_red[t] = fmaxf(a4, 0.0f) * cb2[t] + dotc;   // bv partial + cw2b.obs partial
  }
  __syncthreads();
  for (int o = t; o < ADIM; o += 128) {
    float a = ab2b[o];
    for (int h = 0; h < 128; ++h) a += s_hb[h] * ab2[h * ADIM + o];
    out[b * ADIM + o] = a;
  }
  for (int s = 64; s > 0; s >>= 1) {
    __syncthreads();
    if (t < s) s_red[t] += s_red[t + s];
  }
  if (t == 0) {
    out[131840 + b] = s_red[0] + cb2b[0];      // v partial; critic blocks add rest
    out[131072 + b] = (float)action[b];        // action as float
  }
}

// ---------------- Kernel 2: producer/consumer streaming GEMM ----------------
// Waves 4-7: pure global_load_lds streams of W f32 (copy-style, no barriers).
// Waves 0-3: MFMA consumers (A from L2 obsT, B from LDS ring via XOR slots).
// Handshake: per-chunk flags (producer vmcnt-counted) + done counters.
__global__ __launch_bounds__(512, 1) void khyper(
    const unsigned short* __restrict__ obsT,
    const float* __restrict__ aw2, const float* __restrict__ aw2b,
    const float* __restrict__ cw2,
    const float* __restrict__ ws_ha, const float* __restrict__ ws_hc,
    float* __restrict__ d_out)
{
  __shared__ __align__(16) char ring[RING * 16384];  // 80 KB W f32 chunks
  __shared__ unsigned sync[80];                      // [0..63]=flags[16][4], [64..79]=done[16]

  const int tid = threadIdx.x, blk = blockIdx.x;
  const int wv = tid >> 6, lane = tid & 63;
  const int lrow = lane & 15, grp = lane >> 4;

  // Roles: 0..1023 actor (o=blk>>1, kq=blk&1); 1024..1031 bias; 1032..1033 critic
  int wtype, o0 = 0, kq;
  const char* rowbase;
  size_t rowstride;
  if (blk < 1024) {
    wtype = 0; o0 = blk >> 1; kq = blk & 1;
    rowbase = (const char*)(aw2 + (size_t)o0 * SDIM);
    rowstride = (size_t)ADIM * SDIM * 4;
  } else if (blk < 1032) {
    const int idx = blk - 1024;
    wtype = 1; o0 = (idx >> 1) * 128; kq = idx & 1;
    rowbase = (const char*)(aw2b + (size_t)o0 * SDIM);
    rowstride = SDIM * 4;
  } else {
    wtype = 2; kq = blk - 1032;
    rowbase = (const char*)cw2;
    rowstride = SDIM * 4;
  }

  if (tid < 80) sync[tid] = 0;
  __syncthreads();                                   // only barrier in the kernel

  if (wv >= 4) {
    // ================= PRODUCER (waves 4..7) =================
    const int w = wv - 4;
    const char* src[4];
#pragma unroll
    for (int j = 0; j < 4; ++j) {
      const int row = 32 * w + 8 * j + (lane >> 3);
      const int slot = lane & 7;
      src[j] = rowbase + (size_t)row * rowstride + kq * 2048
             + ((slot ^ (row & 7)) << 4);
    }
#pragma unroll 1
    for (int c = 0; c < NCHUNK; ++c) {
      if (c >= RING) {
        while (*(volatile unsigned*)&sync[64 + c - RING] < 4u)
          __builtin_amdgcn_s_sleep(2);
      }
      char* dst = ring + (c % RING) * 16384 + w * 4096;
#pragma unroll
      for (int j = 0; j < 4; ++j)
        gll16(src[j] + (size_t)c * 128, dst + j * 1024);
      if (c >= 4) {
        asm volatile("s_waitcnt vmcnt(16)" ::: "memory");
        *(volatile unsigned*)&sync[(c - 4) * 4 + w] = 1;
      }
    }
    asm volatile("s_waitcnt vmcnt(12)" ::: "memory");
    *(volatile unsigned*)&sync[12 * 4 + w] = 1;
    asm volatile("s_waitcnt vmcnt(8)" ::: "memory");
    *(volatile unsigned*)&sync[13 * 4 + w] = 1;
    asm volatile("s_waitcnt vmcnt(4)" ::: "memory");
    *(volatile unsigned*)&sync[14 * 4 + w] = 1;
    asm volatile("s_waitcnt vmcnt(0)" ::: "memory");
    *(volatile unsigned*)&sync[15 * 4 + w] = 1;
    return;
  }

  // ================= CONSUMER (waves 0..3) =================
  const int m0 = wv * 64;
  const unsigned short* pA[4];
#pragma unroll
  for (int mf = 0; mf < 4; ++mf)
    pA[mf] = obsT + (((size_t)(kq * 16) * 4 + grp) * 256 + (m0 + mf * 16 + lrow)) * 8;

  // B read offsets: frag nf, quad q -> row=nf*16+lrow, slot=(2*grp+q)^(row&7)
  int boff[8][2];
#pragma unroll
  for (int nf = 0; nf < 8; ++nf) {
    const int row = nf * 16 + lrow;
#pragma unroll
    for (int q = 0; q < 2; ++q)
      boff[nf][q] = row * 128 + (((2 * grp + q) ^ (row & 7)) << 4);
  }

  f32x4 acc[4][8];
#pragma unroll
  for (int mf = 0; mf < 4; ++mf)
#pragma unroll
    for (int nf = 0; nf < 8; ++nf) acc[mf][nf] = (f32x4)(0.0f);

#pragma unroll 1
  for (int c = 0; c < NCHUNK; ++c) {
    {
      const volatile unsigned* fl = &sync[c * 4];
      while (fl[0] == 0u || fl[1] == 0u || fl[2] == 0u || fl[3] == 0u)
        __builtin_amdgcn_s_sleep(2);
    }
    const char* wb = ring + (c % RING) * 16384;
    bf16x8 af[4];
#pragma unroll
    for (int mf = 0; mf < 4; ++mf)
      af[mf] = *(const bf16x8*)(pA[mf] + (size_t)c * 8192);
#pragma unroll
    for (int nf = 0; nf < 8; ++nf) {
      f32x4 x = *(const f32x4*)(wb + boff[nf][0]);
      f32x4 y = *(const f32x4*)(wb + boff[nf][1]);
      union { bf16x8 v; unsigned u[4]; } p;
      p.u[0] = cvtpk(x[0], x[1]); p.u[1] = cvtpk(x[2], x[3]);
      p.u[2] = cvtpk(y[0], y[1]); p.u[3] = cvtpk(y[2], y[3]);
#pragma unroll
      for (int mf = 0; mf < 4; ++mf)
        acc[mf][nf] = __builtin_amdgcn_mfma_f32_16x16x32_bf16(af[mf], p.v, acc[mf][nf], 0, 0, 0);
    }
    asm volatile("s_waitcnt lgkmcnt(0)" ::: "memory");
    if (lane == 0) atomicAdd(&sync[64 + c], 1u);
  }

  // ---- epilogue ----
  if (wtype == 1) {
    // G2[b, o0+row] added directly
#pragma unroll
    for (int mf = 0; mf < 4; ++mf) {
      const int b = m0 + mf * 16 + grp * 4;
#pragma unroll
      for (int nf = 0; nf < 8; ++nf) {
        const int col = o0 + nf * 16 + lrow;
#pragma unroll
        for (int r = 0; r < 4; ++r)
          atomicAdd(&d_out[(size_t)(b + r) * ADIM + col], acc[mf][nf][r]);
      }
    }
  } else {
    const float* hw = (wtype == 0) ? ws_ha : ws_hc;
#pragma unroll
    for (int mf = 0; mf < 4; ++mf) {
      const int b = m0 + mf * 16 + grp * 4;
      float val[4] = {0.f, 0.f, 0.f, 0.f};
#pragma unroll
      for (int nf = 0; nf < 8; ++nf) {
        const int h = nf * 16 + lrow;
#pragma unroll
        for (int r = 0; r < 4; ++r)
          val[r] += hw[(size_t)(b + r) * 128 + h] * acc[mf][nf][r];
      }
#pragma unroll
      for (int r = 0; r < 4; ++r) {
        float v = val[r];
        v += __shfl_xor(v, 1, 64);
        v += __shfl_xor(v, 2, 64);
        v += __shfl_xor(v, 4, 64);
        v += __shfl_xor(v, 8, 64);
        val[r] = v;
      }
      if (lrow == 0) {
#pragma unroll
        for (int r = 0; r < 4; ++r) {
          if (wtype == 0) atomicAdd(&d_out[(size_t)(b + r) * ADIM + o0], val[r]);
          else            atomicAdd(&d_out[131840 + b + r], val[r]);
        }
      }
    }
  }
}

// ---------------- Kernel 3: log_softmax / entropy / log_prob ----------------
__global__ __launch_bounds__(256) void kfinal(const int* __restrict__ action,
                                              float* __restrict__ d_out)
{
  const int b = blockIdx.x, t = threadIdx.x;
  const float* lrow = d_out + (size_t)b * ADIM;
  __shared__ float sM[4], sS[4], sT[4];

  const float x0 = lrow[t], x1 = lrow[t + 256];
  float m = fmaxf(x0, x1);
#pragma unroll
  for (int s = 1; s < 64; s <<= 1) m = fmaxf(m, __shfl_xor(m, s, 64));
  const int wv = t >> 6, ln = t & 63;
  if (ln == 0) sM[wv] = m;
  __syncthreads();
  m = fmaxf(fmaxf(sM[0], sM[1]), fmaxf(sM[2], sM[3]));

  const float d0 = x0 - m, d1 = x1 - m;
  const float e0 = expf(d0), e1 = expf(d1);
  float s1 = e0 + e1;
  float s2 = e0 * d0 + e1 * d1;
#pragma unroll
  for (int s = 1; s < 64; s <<= 1) {
    s1 += __shfl_xor(s1, s, 64);
    s2 += __shfl_xor(s2, s, 64);
  }
  if (ln == 0) { sS[wv] = s1; sT[wv] = s2; }
  __syncthreads();
  if (t == 0) {
    const float S = sS[0] + sS[1] + sS[2] + sS[3];
    const float T = sT[0] + sT[1] + sT[2] + sT[3];
    const float lnS = logf(S);
    const int a = action[b];
    d_out[131328 + b] = (lrow[a] - m) - lnS;   // log_prob
    d_out[131584 + b] = lnS - T / S;           // entropy
  }
}

extern "C" void kernel_launch(void* const* d_in, const int* in_sizes, int n_in,
                              void* d_out_v, int out_size, void* d_ws, size_t ws_size,
                              hipStream_t stream) {
  const float* obs   = (const float*)d_in[0];
  const float* task  = (const float*)d_in[1];
  const int*   action= (const int*)  d_in[2];
  const float* we1   = (const float*)d_in[3];
  const float* be1   = (const float*)d_in[4];
  const float* we2   = (const float*)d_in[5];
  const float* be2   = (const float*)d_in[6];
  const float* aw1   = (const float*)d_in[7];
  const float* aw1b  = (const float*)d_in[8];
  const float* aw2   = (const float*)d_in[9];
  const float* aw2b  = (const float*)d_in[10];
  const float* ab1   = (const float*)d_in[11];
  const float* ab1b  = (const float*)d_in[12];
  const float* ab2   = (const float*)d_in[13];
  const float* ab2b  = (const float*)d_in[14];
  const float* cw1   = (const float*)d_in[15];
  const float* cw1b  = (const float*)d_in[16];
  const float* cw2   = (const float*)d_in[17];
  const float* cw2b  = (const float*)d_in[18];
  const float* cb1   = (const float*)d_in[19];
  const float* cb1b  = (const float*)d_in[20];
  const float* cb2   = (const float*)d_in[21];
  const float* cb2b  = (const float*)d_in[22];
  float* out = (float*)d_out_v;
  float* ws_ha = (float*)d_ws;                        // [256][128] f32
  float* ws_hc = ws_ha + 256 * 128;                   // [256][128] f32
  unsigned short* obsT = (unsigned short*)(ws_hc + 256 * 128);  // [32][4][256][8] bf16

  kprep<<<256, 128, 0, stream>>>(obs, task, action, we1, be1, we2, be2, aw1, aw1b,
                                 ab1, ab1b, ab2, ab2b, cw1, cw1b, cb1, cb1b,
                                 cb2, cb2b, cw2b, ws_ha, ws_hc, obsT, out);
  // 1024 actor + 8 bias + 2 critic
  khyper<<<1034, 512, 0, stream>>>(obsT, aw2, aw2b, cw2, ws_ha, ws_hc, out);
  kfinal<<<256, 256, 0, stream>>>(action, out);
}